// Round 5
// baseline (136.043 us; speedup 1.0000x reference)
//
#include <hip/hip_runtime.h>
#include <stdint.h>

#define BS 7
#define HM 50
#define WM 50
#define HH 56
#define WW 56
#define PLANE_IN  (HM * WM)        // 2500
#define PLANE_OUT (HH * WW)        // 3136
#define NPLANES   (64 * 256)       // 16384
#define COUNT_M   51380224.0f      // 64*256*56*56 = 49 * 2^20, exact in fp32
#define PPB       8                // planes per block (both kernels)
#define NBLOCKS   (NPLANES / PPB)  // 2048
#define ROWS      (PPB * HM)       // 400 seed rows per block

typedef unsigned long long u64;

// Kernel 1 (rewritten, ballot-based): 2048 blocks x 8 planes.
// One wave-iteration = one 50-float seed row -> __ballot -> in-register 7-wide
// row dilation -> LDS store. NO LDS atomics anywhere (round-4's per-cell
// atomicOr + 256-way atomicAdd were the suspected DS-pipe serialization).
__global__ __launch_bounds__(256) void dropblock_dilate(
    const float* __restrict__ mask,
    u64* __restrict__ bitmap,
    unsigned* __restrict__ counts)
{
    __shared__ u64 rowdil[ROWS];   // 3.2 KB: row-dilated seed rows, flat [8][50]
    __shared__ unsigned wsum[4];

    const int tid  = threadIdx.x;
    const int lane = tid & 63;
    const int wave = tid >> 6;

    const float* mp = mask + (size_t)blockIdx.x * (PPB * PLANE_IN);

    // 400 rows / 4 waves = 100 rows per wave; unroll 2 for MLP.
    for (int rr = wave; rr < ROWS; rr += 8) {
        const int r2 = rr + 4;
        float a = (lane < WM) ? mp[(size_t)rr * WM + lane] : 0.f;
        float b = (lane < WM) ? mp[(size_t)r2 * WM + lane] : 0.f;
        u64 ba = __ballot(a != 0.f);
        u64 bb = __ballot(b != 0.f);
        if (lane == 0) {
            u64 s = ba | (ba << 1); s |= s << 2; s |= s << 3;  // shifts 0..6
            rowdil[rr] = s;
            u64 t = bb | (bb << 1); t |= t << 2; t |= t << 3;
            rowdil[r2] = t;
        }
    }
    __syncthreads();

    // Column dilation + invert + popcount + coalesced bitmap store.
    unsigned pc = 0;
    for (int i = tid; i < PPB * HH; i += 256) {  // 448
        const int plane = i / HH;
        const int h = i - plane * HH;
        int lo = h - (BS - 1); if (lo < 0) lo = 0;
        int hi = h;            if (hi > HM - 1) hi = HM - 1;
        u64 d = 0ULL;
        for (int r = lo; r <= hi; ++r) d |= rowdil[plane * HM + r];
        u64 keep = ~d & ((1ULL << 56) - 1ULL);
        bitmap[(size_t)blockIdx.x * (PPB * HH) + i] = keep;
        pc += (unsigned)__popcll(keep);
    }

    // Wave-shuffle count reduction (no LDS atomics).
#pragma unroll
    for (int off = 32; off; off >>= 1) pc += __shfl_down(pc, off, 64);
    if (lane == 0) wsum[wave] = pc;
    __syncthreads();
    if (tid == 0)
        counts[blockIdx.x] = wsum[0] + wsum[1] + wsum[2] + wsum[3];
}

// Kernel 2: UNCHANGED from round 4 (A/B isolation -- delta total == delta K1).
// Fused reduce + scale. 2048 blocks x 8 planes; per-block count sum = 8 KB;
// streams 6272 contiguous float4 stores, skipping x loads for all-zero
// nibbles (~99.4% of pixels dropped).
__global__ __launch_bounds__(256) void dropblock_scale(
    const float* __restrict__ x,
    const u64* __restrict__ bitmap,
    const unsigned* __restrict__ counts,
    float* __restrict__ out)
{
    __shared__ u64 bitsLDS[PPB * HH];  // 448 words
    __shared__ unsigned wsum[4];
    __shared__ float s_scale;

    const int tid = threadIdx.x;

    // Bitmap loads first (they cover the count-sum latency).
    for (int i = tid; i < PPB * HH; i += 256)
        bitsLDS[i] = bitmap[(size_t)blockIdx.x * (PPB * HH) + i];

    // Sum 2048 per-block counts: 2 uint4 per thread.
    const uint4* cp = reinterpret_cast<const uint4*>(counts);
    uint4 a = cp[tid], b = cp[tid + 256];
    unsigned s = a.x + a.y + a.z + a.w + b.x + b.y + b.z + b.w;
#pragma unroll
    for (int off = 32; off; off >>= 1) s += __shfl_down(s, off, 64);
    if ((tid & 63) == 0) wsum[tid >> 6] = s;
    __syncthreads();
    if (tid == 0) s_scale = COUNT_M / (float)(wsum[0] + wsum[1] + wsum[2] + wsum[3]);
    __syncthreads();

    const float scale = s_scale;
    // 8 contiguous planes = 25088 floats = 6272 float4 per block.
    const size_t fbase = (size_t)blockIdx.x * (PPB * PLANE_OUT / 4);
    const float4* xp = reinterpret_cast<const float4*>(x) + fbase;
    float4* op = reinterpret_cast<float4*>(out) + fbase;

    for (int j = tid; j < PPB * PLANE_OUT / 4; j += 256) {
        // 14 float4 per row; bitmap word = j/14 (flattened [8][56] layout).
        const int wword = j / 14;
        const int q = j - 14 * wword;
        const unsigned m4 = (unsigned)((bitsLDS[wword] >> (4 * q)) & 0xFULL);
        float4 o = {0.f, 0.f, 0.f, 0.f};
        if (m4) {
            float4 v = xp[j];
            o.x = (m4 & 1u) ? v.x * scale : 0.f;
            o.y = (m4 & 2u) ? v.y * scale : 0.f;
            o.z = (m4 & 4u) ? v.z * scale : 0.f;
            o.w = (m4 & 8u) ? v.w * scale : 0.f;
        }
        op[j] = o;
    }
}

extern "C" void kernel_launch(void* const* d_in, const int* in_sizes, int n_in,
                              void* d_out, int out_size, void* d_ws, size_t ws_size,
                              hipStream_t stream)
{
    const float* x    = (const float*)d_in[0];   // (64,256,56,56) f32
    const float* mask = (const float*)d_in[1];   // (64,256,50,50) f32
    float* out = (float*)d_out;

    // d_ws layout:
    //   [0, 8KB)    counts[2048] (u32), fully written by kernel 1
    //   [64KB, ..)  bitmap: 2048*448 u64 = 7.34 MB
    unsigned* counts = (unsigned*)d_ws;
    u64* bitmap = (u64*)((char*)d_ws + 65536);

    dropblock_dilate<<<NBLOCKS, 256, 0, stream>>>(mask, bitmap, counts);
    dropblock_scale<<<NBLOCKS, 256, 0, stream>>>(x, bitmap, counts, out);
}